// Round 5
// baseline (251.202 us; speedup 1.0000x reference)
//
#include <hip/hip_runtime.h>
#include <math.h>

#define D_   512
#define H_   4
#define KC   128
#define T_   1024
#define B_   4
#define NEG_ -10000.0f

typedef short bf16x8 __attribute__((ext_vector_type(8)));
typedef float f32x4  __attribute__((ext_vector_type(4)));

__device__ __forceinline__ ushort f2b_rne(float x) {
    unsigned u = __float_as_uint(x);
    u += 0x7fffu + ((u >> 16) & 1u);
    return (ushort)(u >> 16);
}

// ---------------------------------------------------------------------------
// fused fp32 -> bf16 converter for all 6 tensors (one launch)
// ---------------------------------------------------------------------------
__global__ __launch_bounds__(256) void cvt_all(const float* __restrict__ x,
                                               const float* __restrict__ c,
                                               const float* __restrict__ w0,
                                               const float* __restrict__ w1,
                                               const float* __restrict__ w2,
                                               const float* __restrict__ w3,
                                               ushort* xo, ushort* co,
                                               ushort* o0, ushort* o1,
                                               ushort* o2, ushort* o3)
{
    const int blk = blockIdx.x;
    const float* src; ushort* dst; int base;
    if (blk < 1024)      { src = x; dst = xo; base = blk; }
    else if (blk < 2048) { src = c; dst = co; base = blk - 1024; }
    else {
        const int w = (blk - 2048) >> 7;
        base = (blk - 2048) & 127;
        src = (w == 0) ? w0 : (w == 1) ? w1 : (w == 2) ? w2 : w3;
        dst = (w == 0) ? o0 : (w == 1) ? o1 : (w == 2) ? o2 : o3;
    }
    const int i = base * 256 + threadIdx.x;
    const float4 a = ((const float4*)src)[2 * i];
    const float4 b = ((const float4*)src)[2 * i + 1];
    uint4 r;
    r.x = (unsigned)f2b_rne(a.x) | ((unsigned)f2b_rne(a.y) << 16);
    r.y = (unsigned)f2b_rne(a.z) | ((unsigned)f2b_rne(a.w) << 16);
    r.z = (unsigned)f2b_rne(b.x) | ((unsigned)f2b_rne(b.y) << 16);
    r.w = (unsigned)f2b_rne(b.z) | ((unsigned)f2b_rne(b.w) << 16);
    ((uint4*)dst)[i] = r;
}

// ---------------------------------------------------------------------------
// bf16 MFMA GEMM: C = A * W^T + bias.  Tile 64x64, BK=64, 8 iterations,
// register-prefetch + LDS double-buffer, ONE barrier per iteration.
// XOR chunk-swizzle on LDS tiles (chunk ^= row&7) -> 2-way max aliasing.
//  mode 0: fp32 row-major [M,512]
//  mode 1: bf16 head-split [B,H,T,KC]
//  mode 2: bf16 head-split TRANSPOSED [B,H,KC,T]  (for V)
// ---------------------------------------------------------------------------
__global__ __launch_bounds__(256) void gemm_mfma(const ushort* __restrict__ A,
                                                 const ushort* __restrict__ W,
                                                 const float* __restrict__ bias,
                                                 void* __restrict__ Cout, int mode)
{
    __shared__ __align__(16) ushort As[2][64 * 64];   // 2 x 8 KB
    __shared__ __align__(16) ushort Bs[2][64 * 64];   // 2 x 8 KB

    const int tid = threadIdx.x;
    const int m0 = blockIdx.x * 64;
    const int n0 = blockIdx.y * 64;
    const int lane = tid & 63;
    const int wid  = tid >> 6;
    const int wm = (wid >> 1) * 32;
    const int wn = (wid & 1) * 32;
    const int c_   = lane & 15;
    const int quad = lane >> 4;

    // staging ownership: store s (s=0,1): row = s*32 + (tid>>3), chunk = tid&7
    const int sr = tid >> 3;        // + s*32
    const int sc = tid & 7;
    const ushort* ga = A + (size_t)(m0 + sr) * D_ + sc * 8;
    const ushort* gb = W + (size_t)(n0 + sr) * D_ + sc * 8;

    f32x4 acc[2][2] = {};
    uint4 areg[2], breg[2];

    // prologue: load tile 0
#pragma unroll
    for (int s = 0; s < 2; s++) {
        areg[s] = *(const uint4*)(ga + (size_t)s * 32 * D_);
        breg[s] = *(const uint4*)(gb + (size_t)s * 32 * D_);
    }

    for (int it = 0; it < 8; it++) {
        const int buf = it & 1;
        // ds_write staged regs (swizzled)
#pragma unroll
        for (int s = 0; s < 2; s++) {
            const int r = s * 32 + sr;
            const int cs = (sc ^ (r & 7)) * 8;
            *(uint4*)(&As[buf][r * 64 + cs]) = areg[s];
            *(uint4*)(&Bs[buf][r * 64 + cs]) = breg[s];
        }
        // prefetch next k-tile
        if (it < 7) {
            const size_t ko = (size_t)(it + 1) * 64;
#pragma unroll
            for (int s = 0; s < 2; s++) {
                areg[s] = *(const uint4*)(ga + (size_t)s * 32 * D_ + ko);
                breg[s] = *(const uint4*)(gb + (size_t)s * 32 * D_ + ko);
            }
        }
        __syncthreads();

#pragma unroll
        for (int kc = 0; kc < 2; kc++) {
            bf16x8 af[2], bf[2];
#pragma unroll
            for (int mt = 0; mt < 2; mt++) {
                const int r = wm + mt * 16 + c_;
                af[mt] = *(const bf16x8*)(&As[buf][r * 64 + (((kc * 4 + quad) ^ (r & 7)) * 8)]);
            }
#pragma unroll
            for (int nt = 0; nt < 2; nt++) {
                const int r = wn + nt * 16 + c_;
                bf[nt] = *(const bf16x8*)(&Bs[buf][r * 64 + (((kc * 4 + quad) ^ (r & 7)) * 8)]);
            }
#pragma unroll
            for (int mt = 0; mt < 2; mt++)
#pragma unroll
                for (int nt = 0; nt < 2; nt++)
                    acc[mt][nt] = __builtin_amdgcn_mfma_f32_16x16x32_bf16(
                        af[mt], bf[nt], acc[mt][nt], 0, 0, 0);
        }
    }

    // epilogue
#pragma unroll
    for (int mt = 0; mt < 2; mt++)
#pragma unroll
        for (int nt = 0; nt < 2; nt++) {
            const int n = n0 + wn + nt * 16 + c_;
            const float bn = bias[n];
            const int mb = m0 + wm + mt * 16 + quad * 4;
            if (mode == 2) {
                const int b = mb >> 10, t0 = mb & (T_ - 1);
                const int h = n >> 7, kc = n & (KC - 1);
                ushort4 pk;
                pk.x = f2b_rne(acc[mt][nt][0] + bn);
                pk.y = f2b_rne(acc[mt][nt][1] + bn);
                pk.z = f2b_rne(acc[mt][nt][2] + bn);
                pk.w = f2b_rne(acc[mt][nt][3] + bn);
                *(ushort4*)((ushort*)Cout +
                    ((size_t)((b * H_ + h) * KC + kc)) * T_ + t0) = pk;
            } else {
#pragma unroll
                for (int r = 0; r < 4; r++) {
                    const int m = mb + r;
                    const float val = acc[mt][nt][r] + bn;
                    if (mode == 1) {
                        const int b = m >> 10, t = m & (T_ - 1);
                        const int h = n >> 7, kc = n & (KC - 1);
                        ((ushort*)Cout)[((size_t)((b * H_ + h) * T_ + t)) * KC + kc] =
                            f2b_rne(val);
                    } else {
                        ((float*)Cout)[(size_t)m * D_ + n] = val;
                    }
                }
            }
        }
}

// ---------------------------------------------------------------------------
// MFMA flash attention, pipelined: register prefetch + double-buffered K/Vt,
// ONE barrier per K/V tile. Q A-frags hoisted to registers. 1-D grid with
// XCD swizzle: bh = (blk&7)*2 + (blk>>7) -> each XCD sees only 2 bh streams.
// ---------------------------------------------------------------------------
__global__ __launch_bounds__(256) void attn_mfma(const ushort* __restrict__ qg,
                                                 const ushort* __restrict__ kg,
                                                 const ushort* __restrict__ vtg,
                                                 const float* __restrict__ mask,
                                                 const float* __restrict__ relk,
                                                 const float* __restrict__ relv,
                                                 ushort* __restrict__ outp)
{
    const int blk = blockIdx.x;
    const int bh  = (blk & 7) * 2 + (blk >> 7);
    const int i0  = ((blk >> 3) & 15) * 64;
    const int b   = bh >> 2;
    const int h   = bh & 3;
    const int tid  = threadIdx.x;
    const int lane = tid & 63;
    const int wid  = tid >> 6;
    const int c_   = lane & 15;
    const int quad = lane >> 4;
    const int c7   = c_ & 7;
    const int row0 = 16 * wid;

    __shared__ __align__(16) ushort Qs[64 * 128];        // 16 KB
    __shared__ __align__(16) ushort Ks[2][64 * 128];     // 32 KB
    __shared__ __align__(16) ushort Vt[2][128 * 64];     // 32 KB
    __shared__ __align__(16) ushort Ps[64 * 64];         //  8 KB
    __shared__ float relv_s[9 * 128];
    __shared__ float rlog[64][9];
    __shared__ float pdiag[64][9];
    __shared__ float lg[257];
    __shared__ float msk_s[2][64];
    __shared__ float rowm[64];

    const float scale = 0.08838834764831845f;  // 1/sqrt(128)

    // ---- one-time staging: Q tile (swizzled), tables ----
#pragma unroll
    for (int s = 0; s < 4; s++) {
        const int e = s * 256 + tid;
        const int r = e >> 4;
        const int c8 = e & 15;
        const uint4 val = *(const uint4*)(qg + ((size_t)(bh * T_ + i0 + r) * KC + c8 * 8));
        *(uint4*)(Qs + r * 128 + ((c8 ^ (r & 7)) * 8)) = val;
    }
    if (tid < 64) rowm[tid] = mask[b * T_ + i0 + tid];
    for (int e = tid; e < 576; e += 256) ((float*)pdiag)[e] = 0.f;
    for (int e = tid; e < 1152; e += 256) relv_s[e] = relv[e];
    for (int e = tid; e < 257; e += 256) lg[e] = log1pf((float)e);
    __syncthreads();

    // ---- rel-k logits: rlog[r][d] = scale * q[i0+r] . relk[d] ----
    {
        const int r = tid >> 2;
        const int kq4 = tid & 3;
        const int r7 = r & 7;
        float sacc[9];
#pragma unroll
        for (int d = 0; d < 9; d++) sacc[d] = 0.f;
        for (int kk = kq4 * 32; kk < kq4 * 32 + 32; kk++) {
            const float qv = __uint_as_float(
                ((unsigned)Qs[r * 128 + (((kk >> 3) ^ r7) * 8) + (kk & 7)]) << 16);
#pragma unroll
            for (int d = 0; d < 9; d++) sacc[d] += qv * relk[d * KC + kk];
        }
#pragma unroll
        for (int d = 0; d < 9; d++) {
            sacc[d] += __shfl_xor(sacc[d], 1);
            sacc[d] += __shfl_xor(sacc[d], 2);
            if (kq4 == 0) rlog[r][d] = sacc[d] * scale;
        }
    }

    // ---- Q A-fragments into registers (fixed for all tiles) ----
    bf16x8 aqr[4];
#pragma unroll
    for (int ks = 0; ks < 4; ks++)
        aqr[ks] = *(const bf16x8*)(Qs + (row0 + c_) * 128 + (((ks * 4 + quad) ^ c7) * 8));

    float m_run[4], l_run[4];
    f32x4 acco[8] = {};
#pragma unroll
    for (int r4 = 0; r4 < 4; r4++) { m_run[r4] = -1e30f; l_run[r4] = 0.f; }

    const int cstart = (i0 - 256 > 0) ? (i0 - 256) : 0;
    const int cend   = (i0 + 64 + 256 < T_) ? (i0 + 64 + 256) : T_;
    const int ntl    = (cend - cstart) >> 6;

    // staging ownership (register prefetch)
    const int krow = tid >> 4;           // + s*16,  K row, chunk tid&15
    const int kchk = tid & 15;
    const int vch  = tid >> 3;           // + s*32,  V channel, chunk tid&7
    const int vchk = tid & 7;

    uint4 kreg[4], vreg[4];
    float mreg = 0.f;
    {
        const int j0 = cstart;
#pragma unroll
        for (int s = 0; s < 4; s++) {
            kreg[s] = *(const uint4*)(kg + ((size_t)(bh * T_ + j0 + s * 16 + krow) * KC + kchk * 8));
            vreg[s] = *(const uint4*)(vtg + ((size_t)(bh * KC + s * 32 + vch) * T_ + j0 + vchk * 8));
        }
        if (tid < 64) mreg = mask[b * T_ + j0 + tid];
    }

    for (int t = 0; t < ntl; t++) {
        const int j0 = cstart + t * 64;
        const int buf = t & 1;
        ushort* KsB = Ks[buf];
        ushort* VtB = Vt[buf];

        // ---- commit staged regs to LDS (swizzled) ----
#pragma unroll
        for (int s = 0; s < 4; s++) {
            const int r = s * 16 + krow;
            *(uint4*)(KsB + r * 128 + ((kchk ^ (r & 7)) * 8)) = kreg[s];
            const int ch = s * 32 + vch;
            *(uint4*)(VtB + ch * 64 + ((vchk ^ (ch & 7)) * 8)) = vreg[s];
        }
        if (tid < 64) msk_s[buf][tid] = mreg;

        // ---- prefetch next tile into regs ----
        if (t + 1 < ntl) {
            const int jn = j0 + 64;
#pragma unroll
            for (int s = 0; s < 4; s++) {
                kreg[s] = *(const uint4*)(kg + ((size_t)(bh * T_ + jn + s * 16 + krow) * KC + kchk * 8));
                vreg[s] = *(const uint4*)(vtg + ((size_t)(bh * KC + s * 32 + vch) * T_ + jn + vchk * 8));
            }
            if (tid < 64) mreg = mask[b * T_ + jn + tid];
        }

        __syncthreads();  // the ONE barrier: tile t LDS ready, prior readers done

        // ---- S = Q . K^T : 16 MFMAs per wave ----
        f32x4 accs[4] = {};
#pragma unroll
        for (int ks = 0; ks < 4; ks++) {
            const int sw = ((ks * 4 + quad) ^ c7) * 8;
#pragma unroll
            for (int ct = 0; ct < 4; ct++) {
                const bf16x8 bk = *(const bf16x8*)(KsB + (ct * 16 + c_) * 128 + sw);
                accs[ct] = __builtin_amdgcn_mfma_f32_16x16x32_bf16(aqr[ks], bk, accs[ct], 0, 0, 0);
            }
        }

        // ---- online softmax on C-layout fragments ----
        float mskv[4];
#pragma unroll
        for (int ct = 0; ct < 4; ct++) mskv[ct] = msk_s[buf][ct * 16 + c_];

        float alpha4[4];
#pragma unroll
        for (int r4 = 0; r4 < 4; r4++) {
            const int row = row0 + quad * 4 + r4;
            const float rm = rowm[row];
            const int dj = j0 - i0 + c_ - row;  // d at ct=0
            float sv[4];
            float mt = -3e38f;
#pragma unroll
            for (int ct = 0; ct < 4; ct++) {
                const int d = dj + ct * 16;
                const unsigned ad = (unsigned)((d < 0) ? -d : d);
                float s;
                if (rm != 0.f && mskv[ct] != 0.f && ad <= 256u) {
                    s = accs[ct][r4] * scale - lg[ad];
                    const unsigned dw = (unsigned)(d + 4);
                    if (dw <= 8u) s += rlog[row][dw];
                } else {
                    s = NEG_;
                }
                sv[ct] = s;
                mt = fmaxf(mt, s);
            }
            mt = fmaxf(mt, __shfl_xor(mt, 1));
            mt = fmaxf(mt, __shfl_xor(mt, 2));
            mt = fmaxf(mt, __shfl_xor(mt, 4));
            mt = fmaxf(mt, __shfl_xor(mt, 8));
            const float mnew = fmaxf(m_run[r4], mt);
            const float al = __expf(m_run[r4] - mnew);
            alpha4[r4] = al;
            m_run[r4] = mnew;

            const int row7 = row & 7;
            float lt = 0.f;
#pragma unroll
            for (int ct = 0; ct < 4; ct++) {
                const float p = __expf(sv[ct] - mnew);
                sv[ct] = p;
                lt += p;
                Ps[row * 64 + (((2 * ct + (c_ >> 3)) ^ row7) * 8) + c7] = f2b_rne(p);
            }
            lt += __shfl_xor(lt, 1);
            lt += __shfl_xor(lt, 2);
            lt += __shfl_xor(lt, 4);
            lt += __shfl_xor(lt, 8);
            l_run[r4] = l_run[r4] * al + lt;

            if (c_ == 0) {
#pragma unroll
                for (int dd = 0; dd < 9; dd++) pdiag[row][dd] *= al;
            }
#pragma unroll
            for (int ct = 0; ct < 4; ct++) {
                const int d = dj + ct * 16;
                const unsigned dw = (unsigned)(d + 4);
                if (dw <= 8u) pdiag[row][dw] += sv[ct];
            }
        }

        // ---- O *= alpha ; PV: 16 MFMAs per wave (Ps is intra-wave: no barrier) ----
#pragma unroll
        for (int nt = 0; nt < 8; nt++)
#pragma unroll
            for (int r4 = 0; r4 < 4; r4++) acco[nt][r4] *= alpha4[r4];

#pragma unroll
        for (int kt = 0; kt < 2; kt++) {
            const int sw = ((kt * 4 + quad) ^ c7) * 8;
            const bf16x8 ap = *(const bf16x8*)(Ps + (row0 + c_) * 64 + sw);
#pragma unroll
            for (int nt = 0; nt < 8; nt++) {
                const bf16x8 bv = *(const bf16x8*)(VtB + (nt * 16 + c_) * 64 + sw);
                acco[nt] = __builtin_amdgcn_mfma_f32_16x16x32_bf16(ap, bv, acco[nt], 0, 0, 0);
            }
        }
    }

    // ---- epilogue: rel-v via pdiag, normalize, store bf16 [b,t,h,kc] ----
#pragma unroll
    for (int r4 = 0; r4 < 4; r4++) {
        const int row = row0 + quad * 4 + r4;
        const int i = i0 + row;
        const float invl = 1.f / l_run[r4];
        float pd[9];
#pragma unroll
        for (int dd = 0; dd < 9; dd++) {
            const int j = i + dd - 4;
            pd[dd] = (j >= 0 && j < T_) ? pdiag[row][dd] : 0.f;
        }
        ushort* ob = outp + ((size_t)(b * T_ + i) * H_ + h) * KC;
#pragma unroll
        for (int nt = 0; nt < 8; nt++) {
            const int col = nt * 16 + c_;
            float o = acco[nt][r4];
#pragma unroll
            for (int dd = 0; dd < 9; dd++) o += pd[dd] * relv_s[dd * 128 + col];
            ob[col] = f2b_rne(o * invl);
        }
    }
}

// ---------------------------------------------------------------------------
extern "C" void kernel_launch(void* const* d_in, const int* in_sizes, int n_in,
                              void* d_out, int out_size, void* d_ws, size_t ws_size,
                              hipStream_t stream)
{
    const float* x    = (const float*)d_in[0];
    const float* c    = (const float*)d_in[1];
    const float* am   = (const float*)d_in[2];
    const float* Wq   = (const float*)d_in[3];
    const float* bq   = (const float*)d_in[4];
    const float* Wk   = (const float*)d_in[5];
    const float* bk   = (const float*)d_in[6];
    const float* Wv   = (const float*)d_in[7];
    const float* bv   = (const float*)d_in[8];
    const float* Wo   = (const float*)d_in[9];
    const float* bo   = (const float*)d_in[10];
    const float* relk = (const float*)d_in[11];
    const float* relv = (const float*)d_in[12];

    float* out = (float*)d_out;
    char* w8 = (char*)d_ws;
    ushort* qb  = (ushort*)(w8);
    ushort* kb  = (ushort*)(w8 + (4u << 20));
    ushort* vtb = (ushort*)(w8 + (8u << 20));   // [B,H,KC,T]
    ushort* ab  = (ushort*)(w8 + (12u << 20));
    ushort* xb  = (ushort*)(w8 + (16u << 20));
    ushort* cb  = (ushort*)(w8 + (20u << 20));
    ushort* Wqb = (ushort*)(w8 + (24u << 20));
    ushort* Wkb = Wqb + 262144;
    ushort* Wvb = Wkb + 262144;
    ushort* Wob = Wvb + 262144;

    cvt_all<<<2560, 256, 0, stream>>>(x, c, Wq, Wk, Wv, Wo, xb, cb, Wqb, Wkb, Wvb, Wob);

    dim3 ggrid(4096 / 64, D_ / 64);  // (64, 8) = 512 blocks
    gemm_mfma<<<ggrid, 256, 0, stream>>>(xb, Wqb, bq, qb, 1);
    gemm_mfma<<<ggrid, 256, 0, stream>>>(cb, Wkb, bk, kb, 1);
    gemm_mfma<<<ggrid, 256, 0, stream>>>(cb, Wvb, bv, vtb, 2);

    attn_mfma<<<256, 256, 0, stream>>>(qb, kb, vtb, am, relk, relv, ab);

    gemm_mfma<<<ggrid, 256, 0, stream>>>(ab, Wob, bo, (void*)out, 0);
}

// Round 6
// 211.937 us; speedup vs baseline: 1.1853x; 1.1853x over previous
//
#include <hip/hip_runtime.h>
#include <math.h>

#define D_   512
#define H_   4
#define KC   128
#define T_   1024
#define B_   4
#define NEG_ -10000.0f

typedef short bf16x8 __attribute__((ext_vector_type(8)));
typedef float f32x4  __attribute__((ext_vector_type(4)));

__device__ __forceinline__ ushort f2b_rne(float x) {
    unsigned u = __float_as_uint(x);
    u += 0x7fffu + ((u >> 16) & 1u);
    return (ushort)(u >> 16);
}
__device__ __forceinline__ unsigned pack2(float a, float b) {
    return (unsigned)f2b_rne(a) | ((unsigned)f2b_rne(b) << 16);
}

// ---------------------------------------------------------------------------
// Fused q/k/v projection GEMM, fp32 inputs converted to bf16 inline.
// Tile 64x64, BK=64, 8 iters, single LDS buffer, 2 barriers/iter.
// grid (64, 24): y>>3 selects {q from x, k from c, v from c}.
//  q,k -> bf16 head-split [B,H,T,KC]; v -> bf16 transposed [B,H,KC,T]
// ---------------------------------------------------------------------------
__global__ __launch_bounds__(256) void proj_gemm(const float* __restrict__ x,
                                                 const float* __restrict__ cc,
                                                 const float* __restrict__ Wq,
                                                 const float* __restrict__ Wk,
                                                 const float* __restrict__ Wv,
                                                 const float* __restrict__ bq,
                                                 const float* __restrict__ bk,
                                                 const float* __restrict__ bv,
                                                 ushort* __restrict__ qb,
                                                 ushort* __restrict__ kb,
                                                 ushort* __restrict__ vtb)
{
    __shared__ __align__(16) ushort As[64 * 64];   // 8 KB
    __shared__ __align__(16) ushort Bs[64 * 64];   // 8 KB

    const int which = blockIdx.y >> 3;
    const float* A    = (which == 0) ? x  : cc;
    const float* W    = (which == 0) ? Wq : (which == 1) ? Wk : Wv;
    const float* bias = (which == 0) ? bq : (which == 1) ? bk : bv;

    const int m0 = blockIdx.x * 64;
    const int n0 = (blockIdx.y & 7) * 64;
    const int tid = threadIdx.x;
    const int lane = tid & 63;
    const int wid  = tid >> 6;
    const int wm = (wid >> 1) * 32;
    const int wn = (wid & 1) * 32;
    const int c_   = lane & 15;
    const int quad = lane >> 4;

    const int sr = tid >> 2;       // 0..63 staging row
    const int g  = tid & 3;        // 16-float group
    const float* ga = A + (size_t)(m0 + sr) * D_ + g * 16;
    const float* gw = W + (size_t)(n0 + sr) * D_ + g * 16;
    const int sw0 = ((2 * g) ^ (sr & 7)) * 8;
    const int sw1 = ((2 * g + 1) ^ (sr & 7)) * 8;

    f32x4 acc[2][2] = {};

    for (int it = 0; it < 8; it++) {
        const int k0 = it * 64;
        const float4 a0 = *(const float4*)(ga + k0);
        const float4 a1 = *(const float4*)(ga + k0 + 4);
        const float4 a2 = *(const float4*)(ga + k0 + 8);
        const float4 a3 = *(const float4*)(ga + k0 + 12);
        const float4 w0 = *(const float4*)(gw + k0);
        const float4 w1 = *(const float4*)(gw + k0 + 4);
        const float4 w2 = *(const float4*)(gw + k0 + 8);
        const float4 w3 = *(const float4*)(gw + k0 + 12);
        __syncthreads();   // prior iter's fragment reads done
        uint4 pa0, pa1, pw0, pw1;
        pa0.x = pack2(a0.x, a0.y); pa0.y = pack2(a0.z, a0.w);
        pa0.z = pack2(a1.x, a1.y); pa0.w = pack2(a1.z, a1.w);
        pa1.x = pack2(a2.x, a2.y); pa1.y = pack2(a2.z, a2.w);
        pa1.z = pack2(a3.x, a3.y); pa1.w = pack2(a3.z, a3.w);
        pw0.x = pack2(w0.x, w0.y); pw0.y = pack2(w0.z, w0.w);
        pw0.z = pack2(w1.x, w1.y); pw0.w = pack2(w1.z, w1.w);
        pw1.x = pack2(w2.x, w2.y); pw1.y = pack2(w2.z, w2.w);
        pw1.z = pack2(w3.x, w3.y); pw1.w = pack2(w3.z, w3.w);
        *(uint4*)(As + sr * 64 + sw0) = pa0;
        *(uint4*)(As + sr * 64 + sw1) = pa1;
        *(uint4*)(Bs + sr * 64 + sw0) = pw0;
        *(uint4*)(Bs + sr * 64 + sw1) = pw1;
        __syncthreads();

#pragma unroll
        for (int kc = 0; kc < 2; kc++) {
            bf16x8 af[2], bf[2];
#pragma unroll
            for (int mt = 0; mt < 2; mt++) {
                const int r = wm + mt * 16 + c_;
                af[mt] = *(const bf16x8*)(&As[r * 64 + (((kc * 4 + quad) ^ (r & 7)) * 8)]);
            }
#pragma unroll
            for (int nt = 0; nt < 2; nt++) {
                const int r = wn + nt * 16 + c_;
                bf[nt] = *(const bf16x8*)(&Bs[r * 64 + (((kc * 4 + quad) ^ (r & 7)) * 8)]);
            }
#pragma unroll
            for (int mt = 0; mt < 2; mt++)
#pragma unroll
                for (int nt = 0; nt < 2; nt++)
                    acc[mt][nt] = __builtin_amdgcn_mfma_f32_16x16x32_bf16(
                        af[mt], bf[nt], acc[mt][nt], 0, 0, 0);
        }
    }

    // epilogue
#pragma unroll
    for (int mt = 0; mt < 2; mt++)
#pragma unroll
        for (int nt = 0; nt < 2; nt++) {
            const int n = n0 + wn + nt * 16 + c_;
            const float bn = bias[n];
            const int mb = m0 + wm + mt * 16 + quad * 4;
            const int b = mb >> 10;
            const int h = n >> 7, kc = n & (KC - 1);
            if (which == 2) {
                const int t0 = mb & (T_ - 1);
                ushort4 pk;
                pk.x = f2b_rne(acc[mt][nt][0] + bn);
                pk.y = f2b_rne(acc[mt][nt][1] + bn);
                pk.z = f2b_rne(acc[mt][nt][2] + bn);
                pk.w = f2b_rne(acc[mt][nt][3] + bn);
                *(ushort4*)(vtb + ((size_t)((b * H_ + h) * KC + kc)) * T_ + t0) = pk;
            } else {
                ushort* dst = (which == 0) ? qb : kb;
#pragma unroll
                for (int r = 0; r < 4; r++) {
                    const int m = mb + r;
                    const int t = m & (T_ - 1);
                    dst[((size_t)((b * H_ + h) * T_ + t)) * KC + kc] =
                        f2b_rne(acc[mt][nt][r] + bn);
                }
            }
        }
}

// ---------------------------------------------------------------------------
// Output GEMM: out = ab(bf16) * Wo^T + bo  (fp32 out), Wo converted inline.
// ---------------------------------------------------------------------------
__global__ __launch_bounds__(256) void out_gemm(const ushort* __restrict__ ab,
                                                const float* __restrict__ Wo,
                                                const float* __restrict__ bo,
                                                float* __restrict__ out)
{
    __shared__ __align__(16) ushort As[64 * 64];
    __shared__ __align__(16) ushort Bs[64 * 64];

    const int m0 = blockIdx.x * 64;
    const int n0 = blockIdx.y * 64;
    const int tid = threadIdx.x;
    const int lane = tid & 63;
    const int wid  = tid >> 6;
    const int wm = (wid >> 1) * 32;
    const int wn = (wid & 1) * 32;
    const int c_   = lane & 15;
    const int quad = lane >> 4;

    const int sr = tid >> 2;
    const int g  = tid & 3;
    const ushort* ga = ab + (size_t)(m0 + sr) * D_ + g * 16;
    const float*  gw = Wo + (size_t)(n0 + sr) * D_ + g * 16;
    const int sw0 = ((2 * g) ^ (sr & 7)) * 8;
    const int sw1 = ((2 * g + 1) ^ (sr & 7)) * 8;

    f32x4 acc[2][2] = {};

    for (int it = 0; it < 8; it++) {
        const int k0 = it * 64;
        const uint4 u0 = *(const uint4*)(ga + k0);
        const uint4 u1 = *(const uint4*)(ga + k0 + 8);
        const float4 w0 = *(const float4*)(gw + k0);
        const float4 w1 = *(const float4*)(gw + k0 + 4);
        const float4 w2 = *(const float4*)(gw + k0 + 8);
        const float4 w3 = *(const float4*)(gw + k0 + 12);
        __syncthreads();
        uint4 pw0, pw1;
        pw0.x = pack2(w0.x, w0.y); pw0.y = pack2(w0.z, w0.w);
        pw0.z = pack2(w1.x, w1.y); pw0.w = pack2(w1.z, w1.w);
        pw1.x = pack2(w2.x, w2.y); pw1.y = pack2(w2.z, w2.w);
        pw1.z = pack2(w3.x, w3.y); pw1.w = pack2(w3.z, w3.w);
        *(uint4*)(As + sr * 64 + sw0) = u0;
        *(uint4*)(As + sr * 64 + sw1) = u1;
        *(uint4*)(Bs + sr * 64 + sw0) = pw0;
        *(uint4*)(Bs + sr * 64 + sw1) = pw1;
        __syncthreads();

#pragma unroll
        for (int kc = 0; kc < 2; kc++) {
            bf16x8 af[2], bf[2];
#pragma unroll
            for (int mt = 0; mt < 2; mt++) {
                const int r = wm + mt * 16 + c_;
                af[mt] = *(const bf16x8*)(&As[r * 64 + (((kc * 4 + quad) ^ (r & 7)) * 8)]);
            }
#pragma unroll
            for (int nt = 0; nt < 2; nt++) {
                const int r = wn + nt * 16 + c_;
                bf[nt] = *(const bf16x8*)(&Bs[r * 64 + (((kc * 4 + quad) ^ (r & 7)) * 8)]);
            }
#pragma unroll
            for (int mt = 0; mt < 2; mt++)
#pragma unroll
                for (int nt = 0; nt < 2; nt++)
                    acc[mt][nt] = __builtin_amdgcn_mfma_f32_16x16x32_bf16(
                        af[mt], bf[nt], acc[mt][nt], 0, 0, 0);
        }
    }

#pragma unroll
    for (int mt = 0; mt < 2; mt++)
#pragma unroll
        for (int nt = 0; nt < 2; nt++) {
            const int n = n0 + wn + nt * 16 + c_;
            const float bn = bo[n];
            const int mb = m0 + wm + mt * 16 + quad * 4;
#pragma unroll
            for (int r = 0; r < 4; r++)
                out[(size_t)(mb + r) * D_ + n] = acc[mt][nt][r] + bn;
        }
}

// ---------------------------------------------------------------------------
// MFMA flash attention, K/V tile = 128 cols (5 tiles max), 2 barriers/tile.
// Block = 256 thr = 4 waves; wave owns 16 Q rows. XCD swizzle: 2 bh per XCD.
// LDS tiles bf16, XOR chunk-swizzle (chunk ^= row&7).
// ---------------------------------------------------------------------------
__global__ __launch_bounds__(256) void attn_mfma(const ushort* __restrict__ qg,
                                                 const ushort* __restrict__ kg,
                                                 const ushort* __restrict__ vtg,
                                                 const float* __restrict__ mask,
                                                 const float* __restrict__ relk,
                                                 const float* __restrict__ relv,
                                                 ushort* __restrict__ outp)
{
    const int blk = blockIdx.x;
    const int bh  = (blk & 7) * 2 + (blk >> 7);
    const int i0  = ((blk >> 3) & 15) * 64;
    const int b   = bh >> 2;
    const int h   = bh & 3;
    const int tid  = threadIdx.x;
    const int lane = tid & 63;
    const int wid  = tid >> 6;
    const int c_   = lane & 15;
    const int quad = lane >> 4;
    const int c7   = c_ & 7;
    const int row0 = 16 * wid;

    __shared__ __align__(16) ushort Qs[64 * 128];    // 16 KB
    __shared__ __align__(16) ushort Ks[128 * 128];   // 32 KB (rows x k)
    __shared__ __align__(16) ushort Vt[128 * 128];   // 32 KB (ch x t)
    __shared__ __align__(16) ushort Ps[64 * 128];    // 16 KB
    __shared__ float relv_s[9 * 128];
    __shared__ float rlog[64][9];
    __shared__ float pdiag[64][9];
    __shared__ float lg[257];
    __shared__ float msk_s[128];
    __shared__ float rowm[64];

    const float scale = 0.08838834764831845f;  // 1/sqrt(128)

    // ---- one-time staging: Q tile (swizzled), tables ----
#pragma unroll
    for (int s = 0; s < 4; s++) {
        const int e = s * 256 + tid;
        const int r = e >> 4;
        const int c8 = e & 15;
        const uint4 val = *(const uint4*)(qg + ((size_t)(bh * T_ + i0 + r) * KC + c8 * 8));
        *(uint4*)(Qs + r * 128 + ((c8 ^ (r & 7)) * 8)) = val;
    }
    if (tid < 64) rowm[tid] = mask[b * T_ + i0 + tid];
    for (int e = tid; e < 576; e += 256) ((float*)pdiag)[e] = 0.f;
    for (int e = tid; e < 1152; e += 256) relv_s[e] = relv[e];
    for (int e = tid; e < 257; e += 256) lg[e] = log1pf((float)e);
    __syncthreads();

    // ---- rel-k logits: rlog[r][d] = scale * q[i0+r] . relk[d] ----
    {
        const int r = tid >> 2;
        const int kq4 = tid & 3;
        const int r7 = r & 7;
        float sacc[9];
#pragma unroll
        for (int d = 0; d < 9; d++) sacc[d] = 0.f;
        for (int kk = kq4 * 32; kk < kq4 * 32 + 32; kk++) {
            const float qv = __uint_as_float(
                ((unsigned)Qs[r * 128 + (((kk >> 3) ^ r7) * 8) + (kk & 7)]) << 16);
#pragma unroll
            for (int d = 0; d < 9; d++) sacc[d] += qv * relk[d * KC + kk];
        }
#pragma unroll
        for (int d = 0; d < 9; d++) {
            sacc[d] += __shfl_xor(sacc[d], 1);
            sacc[d] += __shfl_xor(sacc[d], 2);
            if (kq4 == 0) rlog[r][d] = sacc[d] * scale;
        }
    }

    // ---- Q A-fragments in registers ----
    bf16x8 aqr[4];
#pragma unroll
    for (int ks = 0; ks < 4; ks++)
        aqr[ks] = *(const bf16x8*)(Qs + (row0 + c_) * 128 + (((ks * 4 + quad) ^ c7) * 8));

    float m_run[4], l_run[4];
    f32x4 acco[8] = {};
#pragma unroll
    for (int r4 = 0; r4 < 4; r4++) { m_run[r4] = -1e30f; l_run[r4] = 0.f; }

    const int cstart = (i0 - 256 > 0) ? (i0 - 256) : 0;
    const int cend   = (i0 + 64 + 256 < T_) ? (i0 + 64 + 256) : T_;
    const int ntl    = (cend - cstart + 127) >> 7;

    const int srow = tid >> 4;   // 0..15 (+ s*16)
    const int schk = tid & 15;   // 16B chunk

    for (int t = 0; t < ntl; t++) {
        const int j0 = cstart + t * 128;

        // issue loads for this tile (before barrier: overlap convergence)
        uint4 kv[8], vv[8];
#pragma unroll
        for (int s = 0; s < 8; s++) {
            const int kr = s * 16 + srow;
            const int jr = j0 + kr;
            const int jcl = (jr < T_) ? jr : (T_ - 1);
            kv[s] = *(const uint4*)(kg + ((size_t)(bh * T_ + jcl) * KC + schk * 8));
            const int ch = s * 16 + srow;
            const int tb = j0 + schk * 8;
            const int tcl = (tb + 8 <= T_) ? tb : (T_ - 8);
            vv[s] = *(const uint4*)(vtg + ((size_t)(bh * KC + ch) * T_ + tcl));
        }
        float mreg = 0.f;
        if (tid < 128) {
            const int jm = j0 + tid;
            mreg = (jm < T_) ? mask[b * T_ + jm] : 0.f;
        }

        __syncthreads();   // prior tile's Ks/Vt reads done

#pragma unroll
        for (int s = 0; s < 8; s++) {
            const int kr = s * 16 + srow;
            *(uint4*)(Ks + kr * 128 + ((schk ^ (kr & 7)) * 8)) = kv[s];
            const int ch = s * 16 + srow;
            *(uint4*)(Vt + ch * 128 + ((schk ^ (ch & 7)) * 8)) = vv[s];
        }
        if (tid < 128) msk_s[tid] = mreg;
        __syncthreads();   // tile staged

        // ---- S = Q . K^T : 32 MFMAs per wave (16 rows x 128 cols) ----
        f32x4 accs[8] = {};
#pragma unroll
        for (int ks = 0; ks < 4; ks++) {
            const int sw = ((ks * 4 + quad) ^ c7) * 8;
#pragma unroll
            for (int ct = 0; ct < 8; ct++) {
                const int r = ct * 16 + c_;
                const bf16x8 bk = *(const bf16x8*)(Ks + r * 128 + (((ks * 4 + quad) ^ (r & 7)) * 8));
                accs[ct] = __builtin_amdgcn_mfma_f32_16x16x32_bf16(aqr[ks], bk, accs[ct], 0, 0, 0);
            }
        }

        // ---- online softmax on C-layout fragments ----
        float mskv[8];
#pragma unroll
        for (int ct = 0; ct < 8; ct++) mskv[ct] = msk_s[ct * 16 + c_];

        float alpha4[4];
#pragma unroll
        for (int r4 = 0; r4 < 4; r4++) {
            const int row = row0 + quad * 4 + r4;
            const float rm = rowm[row];
            const int dj = j0 - i0 + c_ - row;  // d at ct=0
            float sv[8];
            float mt = -3e38f;
#pragma unroll
            for (int ct = 0; ct < 8; ct++) {
                const int d = dj + ct * 16;
                const unsigned ad = (unsigned)((d < 0) ? -d : d);
                float s;
                if (rm != 0.f && mskv[ct] != 0.f && ad <= 256u) {
                    s = accs[ct][r4] * scale - lg[ad];
                    const unsigned dw = (unsigned)(d + 4);
                    if (dw <= 8u) s += rlog[row][dw];
                } else {
                    s = NEG_;
                }
                sv[ct] = s;
                mt = fmaxf(mt, s);
            }
            mt = fmaxf(mt, __shfl_xor(mt, 1));
            mt = fmaxf(mt, __shfl_xor(mt, 2));
            mt = fmaxf(mt, __shfl_xor(mt, 4));
            mt = fmaxf(mt, __shfl_xor(mt, 8));
            const float mnew = fmaxf(m_run[r4], mt);
            const float al = __expf(m_run[r4] - mnew);
            alpha4[r4] = al;
            m_run[r4] = mnew;

            const int row7 = row & 7;
            float lt = 0.f;
#pragma unroll
            for (int ct = 0; ct < 8; ct++) {
                const float p = __expf(sv[ct] - mnew);
                sv[ct] = p;
                lt += p;
                Ps[row * 128 + (((2 * ct + (c_ >> 3)) ^ row7) * 8) + c7] = f2b_rne(p);
            }
            lt += __shfl_xor(lt, 1);
            lt += __shfl_xor(lt, 2);
            lt += __shfl_xor(lt, 4);
            lt += __shfl_xor(lt, 8);
            l_run[r4] = l_run[r4] * al + lt;

            if (c_ == 0) {
#pragma unroll
                for (int dd = 0; dd < 9; dd++) pdiag[row][dd] *= al;
            }
#pragma unroll
            for (int ct = 0; ct < 8; ct++) {
                const int d = dj + ct * 16;
                const unsigned dw = (unsigned)(d + 4);
                if (dw <= 8u) pdiag[row][dw] += sv[ct];
            }
        }

        // ---- O *= alpha ; PV: 32 MFMAs per wave (Ps intra-wave, no barrier) ----
#pragma unroll
        for (int nt = 0; nt < 8; nt++)
#pragma unroll
            for (int r4 = 0; r4 < 4; r4++) acco[nt][r4] *= alpha4[r4];

#pragma unroll
        for (int kt = 0; kt < 4; kt++) {
            const int swp = ((kt * 4 + quad) ^ c7) * 8;
            const bf16x8 ap = *(const bf16x8*)(Ps + (row0 + c_) * 128 + swp);
#pragma unroll
            for (int nt = 0; nt < 8; nt++) {
                const int r = nt * 16 + c_;
                const bf16x8 bv = *(const bf16x8*)(Vt + r * 128 + (((kt * 4 + quad) ^ (r & 7)) * 8));
                acco[nt] = __builtin_amdgcn_mfma_f32_16x16x32_bf16(ap, bv, acco[nt], 0, 0, 0);
            }
        }
    }

    // ---- epilogue: rel-v via pdiag, normalize, store bf16 [b,t,h,kc] ----
#pragma unroll
    for (int r4 = 0; r4 < 4; r4++) {
        const int row = row0 + quad * 4 + r4;
        const int i = i0 + row;
        const float invl = 1.f / l_run[r4];
        float pd[9];
#pragma unroll
        for (int dd = 0; dd < 9; dd++) {
            const int j = i + dd - 4;
            pd[dd] = (j >= 0 && j < T_) ? pdiag[row][dd] : 0.f;
        }
        ushort* ob = outp + ((size_t)(b * T_ + i) * H_ + h) * KC;
#pragma unroll
        for (int nt = 0; nt < 8; nt++) {
            const int col = nt * 16 + c_;
            float o = acco[nt][r4];
#pragma unroll
            for (int dd = 0; dd < 9; dd++) o += pd[dd] * relv_s[dd * 128 + col];
            ob[col] = f2b_rne(o * invl);
        }
    }
}

// ---------------------------------------------------------------------------
extern "C" void kernel_launch(void* const* d_in, const int* in_sizes, int n_in,
                              void* d_out, int out_size, void* d_ws, size_t ws_size,
                              hipStream_t stream)
{
    const float* x    = (const float*)d_in[0];
    const float* c    = (const float*)d_in[1];
    const float* am   = (const float*)d_in[2];
    const float* Wq   = (const float*)d_in[3];
    const float* bq   = (const float*)d_in[4];
    const float* Wk   = (const float*)d_in[5];
    const float* bk   = (const float*)d_in[6];
    const float* Wv   = (const float*)d_in[7];
    const float* bv   = (const float*)d_in[8];
    const float* Wo   = (const float*)d_in[9];
    const float* bo   = (const float*)d_in[10];
    const float* relk = (const float*)d_in[11];
    const float* relv = (const float*)d_in[12];

    float* out = (float*)d_out;
    char* w8 = (char*)d_ws;
    ushort* qb  = (ushort*)(w8);
    ushort* kb  = (ushort*)(w8 + (4u << 20));
    ushort* vtb = (ushort*)(w8 + (8u << 20));   // [B,H,KC,T]
    ushort* ab  = (ushort*)(w8 + (12u << 20));

    proj_gemm<<<dim3(64, 24), 256, 0, stream>>>(x, c, Wq, Wk, Wv, bq, bk, bv,
                                                qb, kb, vtb);

    attn_mfma<<<256, 256, 0, stream>>>(qb, kb, vtb, am, relk, relv, ab);

    out_gemm<<<dim3(64, 8), 256, 0, stream>>>(ab, Wo, bo, out);
}

// Round 8
// 195.039 us; speedup vs baseline: 1.2880x; 1.0866x over previous
//
#include <hip/hip_runtime.h>
#include <math.h>

#define D_   512
#define H_   4
#define KC   128
#define T_   1024
#define B_   4
#define NEG_ -10000.0f

typedef short bf16x8 __attribute__((ext_vector_type(8)));
typedef float f32x4  __attribute__((ext_vector_type(4)));

__device__ __forceinline__ ushort f2b_rne(float x) {
    unsigned u = __float_as_uint(x);
    u += 0x7fffu + ((u >> 16) & 1u);
    return (ushort)(u >> 16);
}
__device__ __forceinline__ unsigned pk2(float a, float b) {
    return (unsigned)f2b_rne(a) | ((unsigned)f2b_rne(b) << 16);
}
__device__ __forceinline__ float b2f_lo(unsigned u) { return __uint_as_float(u << 16); }
__device__ __forceinline__ float b2f_hi(unsigned u) { return __uint_as_float(u & 0xffff0000u); }

#define PLDA 40   // 32 k-elems + 8 pad (80 B rows: conflict-free frag reads)

// ---------------------------------------------------------------------------
// Fused q/k/v projection GEMM, fp32 -> bf16 inline. Tile 128x128, BK=32,
// 16 iters, 4 waves (2x2), wave tile 64x64 (4x4 MFMA). Prefetch issued after
// the staging barrier so it flies under the MFMA phase.
// grid (32, 4, 3): z selects {q from x, k from c, v from c}.
// q,k -> bf16 [B,H,T,KC]; v -> bf16 transposed [B,H,KC,T]
// ---------------------------------------------------------------------------
__global__ __launch_bounds__(256) void proj_gemm(const float* __restrict__ x,
                                                 const float* __restrict__ cc,
                                                 const float* __restrict__ Wq,
                                                 const float* __restrict__ Wk,
                                                 const float* __restrict__ Wv,
                                                 const float* __restrict__ bq,
                                                 const float* __restrict__ bk,
                                                 const float* __restrict__ bv,
                                                 ushort* __restrict__ qb,
                                                 ushort* __restrict__ kb,
                                                 ushort* __restrict__ vtb)
{
    __shared__ __align__(16) ushort As[128 * PLDA];   // 10 KB
    __shared__ __align__(16) ushort Bs[128 * PLDA];   // 10 KB

    const int which = blockIdx.z;
    const float* A    = (which == 0) ? x  : cc;
    const float* W    = (which == 0) ? Wq : (which == 1) ? Wk : Wv;
    const float* bias = (which == 0) ? bq : (which == 1) ? bk : bv;

    const int m0 = blockIdx.x * 128;
    const int n0 = blockIdx.y * 128;
    const int tid = threadIdx.x;
    const int lane = tid & 63;
    const int wid  = tid >> 6;
    const int wm = (wid >> 1) * 64;
    const int wn = (wid & 1) * 64;
    const int c_   = lane & 15;
    const int quad = lane >> 4;

    const int srow  = tid >> 1;          // 0..127
    const int shalf = (tid & 1) * 16;    // 0 / 16 elems
    const float* ga = A + (size_t)(m0 + srow) * D_ + shalf;
    const float* gw = W + (size_t)(n0 + srow) * D_ + shalf;

    f32x4 acc[4][4] = {};
    float4 ar[4], wr[4];

    // prologue: load k-tile 0
#pragma unroll
    for (int p = 0; p < 4; p++) {
        ar[p] = *(const float4*)(ga + p * 4);
        wr[p] = *(const float4*)(gw + p * 4);
    }

    for (int it = 0; it < 16; it++) {
        __syncthreads();   // prior MFMA-phase LDS reads done (also drains loads)
        uint4 ua, ub;
        ua.x = pk2(ar[0].x, ar[0].y); ua.y = pk2(ar[0].z, ar[0].w);
        ua.z = pk2(ar[1].x, ar[1].y); ua.w = pk2(ar[1].z, ar[1].w);
        ub.x = pk2(ar[2].x, ar[2].y); ub.y = pk2(ar[2].z, ar[2].w);
        ub.z = pk2(ar[3].x, ar[3].y); ub.w = pk2(ar[3].z, ar[3].w);
        *(uint4*)(As + srow * PLDA + shalf)     = ua;
        *(uint4*)(As + srow * PLDA + shalf + 8) = ub;
        ua.x = pk2(wr[0].x, wr[0].y); ua.y = pk2(wr[0].z, wr[0].w);
        ua.z = pk2(wr[1].x, wr[1].y); ua.w = pk2(wr[1].z, wr[1].w);
        ub.x = pk2(wr[2].x, wr[2].y); ub.y = pk2(wr[2].z, wr[2].w);
        ub.z = pk2(wr[3].x, wr[3].y); ub.w = pk2(wr[3].z, wr[3].w);
        *(uint4*)(Bs + srow * PLDA + shalf)     = ua;
        *(uint4*)(Bs + srow * PLDA + shalf + 8) = ub;
        __syncthreads();

        if (it < 15) {   // prefetch next k-tile; lands during MFMA phase
            const int k0 = (it + 1) * 32;
#pragma unroll
            for (int p = 0; p < 4; p++) {
                ar[p] = *(const float4*)(ga + k0 + p * 4);
                wr[p] = *(const float4*)(gw + k0 + p * 4);
            }
        }

        bf16x8 af[4], bf[4];
#pragma unroll
        for (int mt = 0; mt < 4; mt++)
            af[mt] = *(const bf16x8*)(As + (wm + mt * 16 + c_) * PLDA + quad * 8);
#pragma unroll
        for (int nt = 0; nt < 4; nt++)
            bf[nt] = *(const bf16x8*)(Bs + (wn + nt * 16 + c_) * PLDA + quad * 8);
#pragma unroll
        for (int mt = 0; mt < 4; mt++)
#pragma unroll
            for (int nt = 0; nt < 4; nt++)
                acc[mt][nt] = __builtin_amdgcn_mfma_f32_16x16x32_bf16(
                    af[mt], bf[nt], acc[mt][nt], 0, 0, 0);
    }

    // epilogue
#pragma unroll
    for (int mt = 0; mt < 4; mt++)
#pragma unroll
        for (int nt = 0; nt < 4; nt++) {
            const int n = n0 + wn + nt * 16 + c_;
            const float bn = bias[n];
            const int mb = m0 + wm + mt * 16 + quad * 4;
            const int b = mb >> 10;
            const int h = n >> 7, kc = n & (KC - 1);
            if (which == 2) {
                const int t0 = mb & (T_ - 1);
                ushort4 pk;
                pk.x = f2b_rne(acc[mt][nt][0] + bn);
                pk.y = f2b_rne(acc[mt][nt][1] + bn);
                pk.z = f2b_rne(acc[mt][nt][2] + bn);
                pk.w = f2b_rne(acc[mt][nt][3] + bn);
                *(ushort4*)(vtb + ((size_t)((b * H_ + h) * KC + kc)) * T_ + t0) = pk;
            } else {
                ushort* dst = (which == 0) ? qb : kb;
#pragma unroll
                for (int r = 0; r < 4; r++) {
                    const int m = mb + r;
                    const int t = m & (T_ - 1);
                    dst[((size_t)((b * H_ + h) * T_ + t)) * KC + kc] =
                        f2b_rne(acc[mt][nt][r] + bn);
                }
            }
        }
}

// ---------------------------------------------------------------------------
// Output GEMM: out = ab(bf16) * Wo^T + bo (fp32 out). Tile 64x128, BK=32,
// wave tile 32x64 (2x4 MFMA). grid (64, 4) = 256 blocks.
// ---------------------------------------------------------------------------
__global__ __launch_bounds__(256) void out_gemm(const ushort* __restrict__ ab,
                                                const float* __restrict__ Wo,
                                                const float* __restrict__ bo,
                                                float* __restrict__ out)
{
    __shared__ __align__(16) ushort As[64 * PLDA];
    __shared__ __align__(16) ushort Bs[128 * PLDA];

    const int m0 = blockIdx.x * 64;
    const int n0 = blockIdx.y * 128;
    const int tid = threadIdx.x;
    const int lane = tid & 63;
    const int wid  = tid >> 6;
    const int wm = (wid >> 1) * 32;
    const int wn = (wid & 1) * 64;
    const int c_   = lane & 15;
    const int quad = lane >> 4;

    const int srA = tid >> 2;            // 0..63
    const int skA = (tid & 3) * 8;       // 0,8,16,24
    const int srW  = tid >> 1;           // 0..127
    const int shW  = (tid & 1) * 16;
    const ushort* ga = ab + (size_t)(m0 + srA) * D_ + skA;
    const float*  gw = Wo + (size_t)(n0 + srW) * D_ + shW;

    f32x4 acc[2][4] = {};
    uint4 areg;
    float4 wr[4];

    areg = *(const uint4*)ga;
#pragma unroll
    for (int p = 0; p < 4; p++) wr[p] = *(const float4*)(gw + p * 4);

    for (int it = 0; it < 16; it++) {
        __syncthreads();
        *(uint4*)(As + srA * PLDA + skA) = areg;
        uint4 ua, ub;
        ua.x = pk2(wr[0].x, wr[0].y); ua.y = pk2(wr[0].z, wr[0].w);
        ua.z = pk2(wr[1].x, wr[1].y); ua.w = pk2(wr[1].z, wr[1].w);
        ub.x = pk2(wr[2].x, wr[2].y); ub.y = pk2(wr[2].z, wr[2].w);
        ub.z = pk2(wr[3].x, wr[3].y); ub.w = pk2(wr[3].z, wr[3].w);
        *(uint4*)(Bs + srW * PLDA + shW)     = ua;
        *(uint4*)(Bs + srW * PLDA + shW + 8) = ub;
        __syncthreads();

        if (it < 15) {
            const int k0 = (it + 1) * 32;
            areg = *(const uint4*)(ga + k0);
#pragma unroll
            for (int p = 0; p < 4; p++) wr[p] = *(const float4*)(gw + k0 + p * 4);
        }

        bf16x8 af[2], bf[4];
#pragma unroll
        for (int mt = 0; mt < 2; mt++)
            af[mt] = *(const bf16x8*)(As + (wm + mt * 16 + c_) * PLDA + quad * 8);
#pragma unroll
        for (int nt = 0; nt < 4; nt++)
            bf[nt] = *(const bf16x8*)(Bs + (wn + nt * 16 + c_) * PLDA + quad * 8);
#pragma unroll
        for (int mt = 0; mt < 2; mt++)
#pragma unroll
            for (int nt = 0; nt < 4; nt++)
                acc[mt][nt] = __builtin_amdgcn_mfma_f32_16x16x32_bf16(
                    af[mt], bf[nt], acc[mt][nt], 0, 0, 0);
    }

#pragma unroll
    for (int mt = 0; mt < 2; mt++)
#pragma unroll
        for (int nt = 0; nt < 4; nt++) {
            const int n = n0 + wn + nt * 16 + c_;
            const float bn = bo[n];
            const int mb = m0 + wm + mt * 16 + quad * 4;
#pragma unroll
            for (int r = 0; r < 4; r++)
                out[(size_t)(mb + r) * D_ + n] = acc[mt][nt][r] + bn;
        }
}

// ---------------------------------------------------------------------------
// Barrier-free MFMA flash attention.
// Block = 256 thr = 4 INDEPENDENT waves; wave w owns Q rows i0blk + 16w.
// K and V^T fragments are loaded DIRECTLY from global (L2-resident via XCD
// swizzle: 2 bh per XCD, ~1 MB working set) — A/B frag layout for 16x16x32
// is exactly "row lane&15, 16B chunk lane>>4" of a row-major matrix.
// Only P round-trips through a small per-wave padded LDS buffer.
// One __syncthreads total (table staging).
// ---------------------------------------------------------------------------
__global__ __launch_bounds__(256) void attn_mfma(const ushort* __restrict__ qg,
                                                 const ushort* __restrict__ kg,
                                                 const ushort* __restrict__ vtg,
                                                 const float* __restrict__ mask,
                                                 const float* __restrict__ relk,
                                                 const float* __restrict__ relv,
                                                 ushort* __restrict__ outp)
{
    const int blk = blockIdx.x;
    const int bh  = (blk & 7) * 2 + (blk >> 7);
    const int i0b = ((blk >> 3) & 15) * 64;
    const int b   = bh >> 2;
    const int h   = bh & 3;
    const int tid  = threadIdx.x;
    const int lane = tid & 63;
    const int wid  = tid >> 6;
    const int c_   = lane & 15;
    const int quad = lane >> 4;
    const int i0w  = i0b + wid * 16;     // this wave's 16 Q rows

    __shared__ float  msk_s[T_];          // 4 KB   mask row for this b
    __shared__ float  relk_s[9 * KC];     // 4.5 KB
    __shared__ float  relv_s[9 * KC];     // 4.5 KB
    __shared__ float  lg[257];            // 1 KB
    __shared__ float  rlog[4 * 16 * 9];   // per-wave regions
    __shared__ float  pdiag[4 * 16 * 9];
    __shared__ __align__(16) ushort Ps[4 * 16 * 72];  // per-wave 16x64, pad 72

    const float scale = 0.08838834764831845f;  // 1/sqrt(128)

    for (int e = tid; e < T_; e += 256) msk_s[e] = mask[b * T_ + e];
    for (int e = tid; e < 9 * KC; e += 256) { relk_s[e] = relk[e]; relv_s[e] = relv[e]; }
    for (int e = tid; e < 257; e += 256) lg[e] = log1pf((float)e);
    for (int e = tid; e < 4 * 16 * 9; e += 256) pdiag[e] = 0.f;
    __syncthreads();   // the only barrier

    // ---- rel-k logits for this wave's 16 rows (q direct from global) ----
    {
        const int r   = lane >> 2;   // 0..15
        const int kq4 = lane & 3;    // k-quarter
        const ushort* qrow = qg + (size_t)(bh * T_ + i0w + r) * KC + kq4 * 32;
        float sacc[9];
#pragma unroll
        for (int d = 0; d < 9; d++) sacc[d] = 0.f;
#pragma unroll
        for (int kk = 0; kk < 32; kk += 2) {
            const unsigned u = *(const unsigned*)(qrow + kk);
            const float q0 = b2f_lo(u), q1 = b2f_hi(u);
            const int kbase = kq4 * 32 + kk;
#pragma unroll
            for (int d = 0; d < 9; d++)
                sacc[d] += q0 * relk_s[d * KC + kbase] + q1 * relk_s[d * KC + kbase + 1];
        }
#pragma unroll
        for (int d = 0; d < 9; d++) {
            sacc[d] += __shfl_xor(sacc[d], 1);
            sacc[d] += __shfl_xor(sacc[d], 2);
            if (kq4 == 0) rlog[(wid * 16 + r) * 9 + d] = sacc[d] * scale;
        }
    }

    // ---- Q A-fragments direct from global ----
    bf16x8 aqr[4];
#pragma unroll
    for (int ks = 0; ks < 4; ks++)
        aqr[ks] = *(const bf16x8*)(qg + (size_t)(bh * T_ + i0w + c_) * KC + (ks * 4 + quad) * 8);

    float rmv[4];
#pragma unroll
    for (int r4 = 0; r4 < 4; r4++) rmv[r4] = msk_s[i0w + quad * 4 + r4];

    float m_run[4], l_run[4];
    f32x4 acco[8] = {};
#pragma unroll
    for (int r4 = 0; r4 < 4; r4++) { m_run[r4] = -1e30f; l_run[r4] = 0.f; }

    const int cs0    = (i0w - 256 > 0) ? (i0w - 256) : 0;
    const int cstart = cs0 & ~63;
    const int cend   = (i0w + 16 + 256 < T_) ? (i0w + 16 + 256) : T_;
    const int ntl    = (cend - cstart + 63) >> 6;

    ushort* Psw = Ps + wid * 16 * 72;
    float*  pdw = pdiag + wid * 16 * 9;
    const float* rlw = rlog + wid * 16 * 9;

    for (int t = 0; t < ntl; t++) {
        const int j0 = cstart + t * 64;

        // ---- S B-frags direct from global K (batched: latency under MFMAs) ----
        bf16x8 kf[4][4];
#pragma unroll
        for (int ct = 0; ct < 4; ct++)
#pragma unroll
            for (int ks = 0; ks < 4; ks++)
                kf[ct][ks] = *(const bf16x8*)(kg +
                    (size_t)(bh * T_ + j0 + ct * 16 + c_) * KC + (ks * 4 + quad) * 8);

        f32x4 accs[4] = {};
#pragma unroll
        for (int ks = 0; ks < 4; ks++)
#pragma unroll
            for (int ct = 0; ct < 4; ct++)
                accs[ct] = __builtin_amdgcn_mfma_f32_16x16x32_bf16(
                    aqr[ks], kf[ct][ks], accs[ct], 0, 0, 0);

        // ---- online softmax on C-layout fragments (all intra-wave) ----
        float mskv[4];
#pragma unroll
        for (int ct = 0; ct < 4; ct++) mskv[ct] = msk_s[j0 + ct * 16 + c_];

        float alpha4[4];
#pragma unroll
        for (int r4 = 0; r4 < 4; r4++) {
            const int row = quad * 4 + r4;       // wave-local 0..15
            const float rm = rmv[r4];
            const int dj = j0 - i0w + c_ - row;  // d at ct=0
            float sv[4];
            float mt = -3e38f;
#pragma unroll
            for (int ct = 0; ct < 4; ct++) {
                const int d = dj + ct * 16;
                const unsigned ad = (unsigned)((d < 0) ? -d : d);
                float s;
                if (rm != 0.f && mskv[ct] != 0.f && ad <= 256u) {
                    s = accs[ct][r4] * scale - lg[ad];
                    const unsigned dw = (unsigned)(d + 4);
                    if (dw <= 8u) s += rlw[row * 9 + dw];
                } else {
                    s = NEG_;
                }
                sv[ct] = s;
                mt = fmaxf(mt, s);
            }
            mt = fmaxf(mt, __shfl_xor(mt, 1));
            mt = fmaxf(mt, __shfl_xor(mt, 2));
            mt = fmaxf(mt, __shfl_xor(mt, 4));
            mt = fmaxf(mt, __shfl_xor(mt, 8));
            const float mnew = fmaxf(m_run[r4], mt);
            const float al = __expf(m_run[r4] - mnew);
            alpha4[r4] = al;
            m_run[r4] = mnew;

            float lt = 0.f;
#pragma unroll
            for (int ct = 0; ct < 4; ct++) {
                const float p = __expf(sv[ct] - mnew);
                sv[ct] = p;
                lt += p;
                Psw[row * 72 + ct * 16 + c_] = f2b_rne(p);
            }
            lt += __shfl_xor(lt, 1);
            lt += __shfl_xor(lt, 2);
            lt += __shfl_xor(lt, 4);
            lt += __shfl_xor(lt, 8);
            l_run[r4] = l_run[r4] * al + lt;

            if (c_ == 0) {
#pragma unroll
                for (int dd = 0; dd < 9; dd++) pdw[row * 9 + dd] *= al;
            }
#pragma unroll
            for (int ct = 0; ct < 4; ct++) {
                const int d = dj + ct * 16;
                const unsigned dw = (unsigned)(d + 4);
                if (dw <= 8u) pdw[row * 9 + dw] += sv[ct];
            }
        }

        // ---- PV: V^T B-frags direct from global; P A-frags from wave LDS ----
        bf16x8 vf[2][8];
#pragma unroll
        for (int nt = 0; nt < 8; nt++)
#pragma unroll
            for (int kt = 0; kt < 2; kt++)
                vf[kt][nt] = *(const bf16x8*)(vtg +
                    (size_t)(bh * KC + nt * 16 + c_) * T_ + j0 + (kt * 4 + quad) * 8);

#pragma unroll
        for (int nt = 0; nt < 8; nt++)
#pragma unroll
            for (int r4 = 0; r4 < 4; r4++) acco[nt][r4] *= alpha4[r4];

        bf16x8 ap[2];
#pragma unroll
        for (int kt = 0; kt < 2; kt++)
            ap[kt] = *(const bf16x8*)(Psw + c_ * 72 + (kt * 4 + quad) * 8);
#pragma unroll
        for (int kt = 0; kt < 2; kt++)
#pragma unroll
            for (int nt = 0; nt < 8; nt++)
                acco[nt] = __builtin_amdgcn_mfma_f32_16x16x32_bf16(
                    ap[kt], vf[kt][nt], acco[nt], 0, 0, 0);
    }

    // ---- epilogue: rel-v via pdiag, normalize, store bf16 [b,t,h,kc] ----
#pragma unroll
    for (int r4 = 0; r4 < 4; r4++) {
        const int row = quad * 4 + r4;
        const int i = i0w + row;
        const float invl = 1.f / l_run[r4];
        float pd[9];
#pragma unroll
        for (int dd = 0; dd < 9; dd++) {
            const int j = i + dd - 4;
            pd[dd] = (j >= 0 && j < T_) ? pdw[row * 9 + dd] : 0.f;
        }
        ushort* ob = outp + ((size_t)(b * T_ + i) * H_ + h) * KC;
#pragma unroll
        for (int nt = 0; nt < 8; nt++) {
            const int col = nt * 16 + c_;
            float o = acco[nt][r4];
#pragma unroll
            for (int dd = 0; dd < 9; dd++) o += pd[dd] * relv_s[dd * KC + col];
            ob[col] = f2b_rne(o * invl);
        }
    }
}

// ---------------------------------------------------------------------------
extern "C" void kernel_launch(void* const* d_in, const int* in_sizes, int n_in,
                              void* d_out, int out_size, void* d_ws, size_t ws_size,
                              hipStream_t stream)
{
    const float* x    = (const float*)d_in[0];
    const float* c    = (const float*)d_in[1];
    const float* am   = (const float*)d_in[2];
    const float* Wq   = (const float*)d_in[3];
    const float* bq   = (const float*)d_in[4];
    const float* Wk   = (const float*)d_in[5];
    const float* bk   = (const float*)d_in[6];
    const float* Wv   = (const float*)d_in[7];
    const float* bv   = (const float*)d_in[8];
    const float* Wo   = (const float*)d_in[9];
    const float* bo   = (const float*)d_in[10];
    const float* relk = (const float*)d_in[11];
    const float* relv = (const float*)d_in[12];

    float* out = (float*)d_out;
    char* w8 = (char*)d_ws;
    ushort* qb  = (ushort*)(w8);
    ushort* kb  = (ushort*)(w8 + (4u << 20));
    ushort* vtb = (ushort*)(w8 + (8u << 20));   // [B,H,KC,T]
    ushort* ab  = (ushort*)(w8 + (12u << 20));

    proj_gemm<<<dim3(32, 4, 3), 256, 0, stream>>>(x, c, Wq, Wk, Wv, bq, bk, bv,
                                                  qb, kb, vtb);

    attn_mfma<<<256, 256, 0, stream>>>(qb, kb, vtb, am, relk, relv, ab);

    out_gemm<<<dim3(64, 4), 256, 0, stream>>>(ab, Wo, bo, out);
}